// Round 4
// baseline (29.191 us; speedup 1.0000x reference)
//
#include <hip/hip_runtime.h>
#include <stdint.h>

// Contrastive loss: B=16384, C=1000, D=128, fp32 in, scalar fp32 out.
// dist = f2 + c2 - 2*cross; loss = sum(relu(1-dist) over j!=target)/B.
//
// Round 4: fat waves. Each wave owns M=64 rows x 256 cols (quarter), so B
// fragments are read (16384/64)x = 64 MB total from L2 instead of 256 MB.
// Grid 256 blocks x 4 waves = 1 block/CU, 1 wave/SIMD. 2 kernels, 256
// block-level atomics (round 3 proved 4096 same-address atomics = 68us).
#define B_N 16384
#define C_N 1000
#define D_N 128
#define MARGIN 1.0f

typedef __attribute__((ext_vector_type(8))) short short8;  // 8 bf16
typedef __attribute__((ext_vector_type(4))) float f32x4;   // MFMA acc

__device__ __forceinline__ short f2bf(float f) {
    union { float f; uint32_t u; } v; v.f = f;
    uint32_t u = v.u;
    return (short)((u + 0x7FFFu + ((u >> 16) & 1u)) >> 16);
}

__device__ __forceinline__ short8 cvt8(const float4& v0, const float4& v1) {
    short8 s;
    s[0] = f2bf(v0.x); s[1] = f2bf(v0.y); s[2] = f2bf(v0.z); s[3] = f2bf(v0.w);
    s[4] = f2bf(v1.x); s[5] = f2bf(v1.y); s[6] = f2bf(v1.z); s[7] = f2bf(v1.w);
    return s;
}

// ---- kernel 1: cls -> bf16 fragment order; c2 (1e30 sentinel past C_N);
//      zero out[0]. Fragment (nb,kk): lane (l15,kg) holds
//      cls[nb*16+l15][kk*32+kg*8 .. +8] at shorts nb*2048 + kk*512 + lane*8.
__global__ __launch_bounds__(64) void prep_kernel(
    const float* __restrict__ cls, short* __restrict__ bpre,
    float* __restrict__ c2p, float* __restrict__ out)
{
    const int nb   = blockIdx.x;       // 0..63
    const int lane = threadIdx.x;      // 0..63
    const int l15  = lane & 15;
    const int kg   = lane >> 4;
    const int col  = nb * 16 + l15;
    const bool valid = col < C_N;

    float sq = 0.f;
    #pragma unroll
    for (int kk = 0; kk < 4; ++kk) {
        float4 v0 = make_float4(0.f, 0.f, 0.f, 0.f);
        float4 v1 = make_float4(0.f, 0.f, 0.f, 0.f);
        if (valid) {
            const float* p = cls + (size_t)col * D_N + kk * 32 + kg * 8;
            v0 = *reinterpret_cast<const float4*>(p);
            v1 = *reinterpret_cast<const float4*>(p + 4);
        }
        sq += v0.x*v0.x + v0.y*v0.y + v0.z*v0.z + v0.w*v0.w
            + v1.x*v1.x + v1.y*v1.y + v1.z*v1.z + v1.w*v1.w;
        *reinterpret_cast<short8*>(bpre + (size_t)(nb * 2048 + kk * 512 + lane * 8))
            = cvt8(v0, v1);
    }
    sq += __shfl_xor(sq, 16);
    sq += __shfl_xor(sq, 32);
    if (lane < 16)
        c2p[nb * 16 + lane] = ((nb * 16 + lane) < C_N) ? sq : 1e30f;
    if (nb == 0 && lane == 0) out[0] = 0.f;
}

// ---- kernel 2: fused GEMM + hinge. Block = 64 rows; wave w = col quarter w.
__global__ __launch_bounds__(256) void closs_kernel(
    const float* __restrict__ feat, const int* __restrict__ tgt,
    const short* __restrict__ bpre, const float* __restrict__ c2p,
    float* __restrict__ out)
{
    const int tid  = threadIdx.x;
    const int wave = tid >> 6;
    const int lane = tid & 63;
    const int l15  = lane & 15;
    const int kg   = lane >> 4;
    const int row0 = blockIdx.x * 64;
    const int nb0  = wave * 16;        // this wave's 16 col-blocks

    // ---- A prologue: 64 rows x K=128 into registers (bf16) + f2 ----
    short8 a[4][4];
    float  sqm[4];
    #pragma unroll
    for (int m = 0; m < 4; ++m) {
        const float* ap = feat + (size_t)(row0 + m * 16 + l15) * D_N + kg * 8;
        float s = 0.f;
        #pragma unroll
        for (int kk = 0; kk < 4; ++kk) {
            float4 v0 = *reinterpret_cast<const float4*>(ap + kk * 32);
            float4 v1 = *reinterpret_cast<const float4*>(ap + kk * 32 + 4);
            s += v0.x*v0.x + v0.y*v0.y + v0.z*v0.z + v0.w*v0.w
               + v1.x*v1.x + v1.y*v1.y + v1.z*v1.z + v1.w*v1.w;
            a[m][kk] = cvt8(v0, v1);
        }
        s += __shfl_xor(s, 16);
        s += __shfl_xor(s, 32);
        sqm[m] = s;   // lane holds f2 of row m*16 + l15
    }
    // t = MARGIN - f2 for this lane's 16 accumulator rows; targets likewise.
    float t[4][4];
    int   tg2[4][4];
    #pragma unroll
    for (int m = 0; m < 4; ++m)
        #pragma unroll
        for (int r = 0; r < 4; ++r) {
            t[m][r]   = MARGIN - __shfl(sqm[m], kg * 4 + r);
            tg2[m][r] = tgt[row0 + m * 16 + kg * 4 + r];
        }

    // ---- main loop over 16 col-blocks: 4 B-frag loads + 16 MFMA + hinge ----
    float hsum = 0.f;
    #pragma unroll 2
    for (int i = 0; i < 16; ++i) {
        const int nb = nb0 + i;
        const short8* bp =
            reinterpret_cast<const short8*>(bpre + (size_t)nb * 2048) + lane;
        short8 b0 = bp[0];
        short8 b1 = bp[64];
        short8 b2 = bp[128];
        short8 b3 = bp[192];
        f32x4 acc[4];
        #pragma unroll
        for (int m = 0; m < 4; ++m) acc[m] = (f32x4){0.f, 0.f, 0.f, 0.f};
        #pragma unroll
        for (int m = 0; m < 4; ++m)
            acc[m] = __builtin_amdgcn_mfma_f32_16x16x32_bf16(a[m][0], b0, acc[m], 0, 0, 0);
        #pragma unroll
        for (int m = 0; m < 4; ++m)
            acc[m] = __builtin_amdgcn_mfma_f32_16x16x32_bf16(a[m][1], b1, acc[m], 0, 0, 0);
        #pragma unroll
        for (int m = 0; m < 4; ++m)
            acc[m] = __builtin_amdgcn_mfma_f32_16x16x32_bf16(a[m][2], b2, acc[m], 0, 0, 0);
        #pragma unroll
        for (int m = 0; m < 4; ++m)
            acc[m] = __builtin_amdgcn_mfma_f32_16x16x32_bf16(a[m][3], b3, acc[m], 0, 0, 0);

        // C/D layout (m89): col = lane&15, row = kg*4 + r.
        const int   col = nb * 16 + l15;
        const float c2v = c2p[col];     // = 1e30 for padded cols -> h = 0
        #pragma unroll
        for (int m = 0; m < 4; ++m)
            #pragma unroll
            for (int r = 0; r < 4; ++r) {
                const float u = __builtin_fmaf(2.0f, acc[m][r], t[m][r] - c2v);
                const float h = fmaxf(0.0f, u);
                hsum += (col != tg2[m][r]) ? h : 0.0f;
            }
    }

    // ---- reduce: wave -> block -> one atomic per block (256 total) ----
    #pragma unroll
    for (int off = 32; off; off >>= 1) hsum += __shfl_down(hsum, off);
    __shared__ float ws[4];
    if (lane == 0) ws[wave] = hsum;
    __syncthreads();
    if (tid == 0)
        atomicAdd(out, (ws[0] + ws[1] + ws[2] + ws[3]) * (1.0f / 16384.0f));
}

extern "C" void kernel_launch(void* const* d_in, const int* in_sizes, int n_in,
                              void* d_out, int out_size, void* d_ws, size_t ws_size,
                              hipStream_t stream) {
    const float* feat = (const float*)d_in[0];
    const int*   tgt  = (const int*)d_in[1];
    const float* cls  = (const float*)d_in[2];
    float*       out  = (float*)d_out;

    short* bpre = (short*)d_ws;                       // 64*2048 shorts = 256 KiB
    float* c2p  = (float*)((char*)d_ws + 64 * 2048 * sizeof(short));  // 4 KiB

    prep_kernel<<<64, 64, 0, stream>>>(cls, bpre, c2p, out);
    closs_kernel<<<256, 256, 0, stream>>>(feat, tgt, bpre, c2p, out);
}

// Round 5
// 28.586 us; speedup vs baseline: 1.0212x; 1.0212x over previous
//
#include <hip/hip_runtime.h>
#include <stdint.h>

// Contrastive loss: B=16384, C=1000, D=128, fp32 in, scalar fp32 out.
// dist = f2 + c2 - 2*cross; loss = sum(relu(1-dist) over j!=target)/B.
//
// Round 5: latency fix. r3(26us,4blk/CU) vs r4(29us,1blk/CU) showed the body
// is L2/L3-LATENCY bound on inner-loop B reloads. Now each block stages its
// 32KB B column-slice (fragment-order, linear) into LDS once; inner loop is
// ds_read_b128 + MFMA. 1024 blocks = 4/CU = 16 waves/CU. No contended atomics
// (r2->r3 proved 4096 same-addr atomics = +48us): block partials + reduce.
#define B_N 16384
#define C_N 1000
#define D_N 128
#define MARGIN 1.0f

typedef __attribute__((ext_vector_type(8))) short short8;  // 8 bf16
typedef __attribute__((ext_vector_type(4))) float f32x4;   // MFMA acc

__device__ __forceinline__ short f2bf(float f) {
    union { float f; uint32_t u; } v; v.f = f;
    uint32_t u = v.u;
    return (short)((u + 0x7FFFu + ((u >> 16) & 1u)) >> 16);
}

__device__ __forceinline__ short8 cvt8(const float4& v0, const float4& v1) {
    short8 s;
    s[0] = f2bf(v0.x); s[1] = f2bf(v0.y); s[2] = f2bf(v0.z); s[3] = f2bf(v0.w);
    s[4] = f2bf(v1.x); s[5] = f2bf(v1.y); s[6] = f2bf(v1.z); s[7] = f2bf(v1.w);
    return s;
}

// ---- kernel 1: cls -> bf16 fragment order + c2 (1e30 sentinel past C_N).
// Fragment (nb,kk): lane (l15,kg) holds cls[nb*16+l15][kk*32+kg*8 .. +8]
// at shorts nb*2048 + kk*512 + lane*8.
__global__ __launch_bounds__(64) void prep_kernel(
    const float* __restrict__ cls, short* __restrict__ bpre,
    float* __restrict__ c2p)
{
    const int nb   = blockIdx.x;       // 0..63
    const int lane = threadIdx.x;      // 0..63
    const int l15  = lane & 15;
    const int kg   = lane >> 4;
    const int col  = nb * 16 + l15;
    const bool valid = col < C_N;

    float sq = 0.f;
    #pragma unroll
    for (int kk = 0; kk < 4; ++kk) {
        float4 v0 = make_float4(0.f, 0.f, 0.f, 0.f);
        float4 v1 = make_float4(0.f, 0.f, 0.f, 0.f);
        if (valid) {
            const float* p = cls + (size_t)col * D_N + kk * 32 + kg * 8;
            v0 = *reinterpret_cast<const float4*>(p);
            v1 = *reinterpret_cast<const float4*>(p + 4);
        }
        sq += v0.x*v0.x + v0.y*v0.y + v0.z*v0.z + v0.w*v0.w
            + v1.x*v1.x + v1.y*v1.y + v1.z*v1.z + v1.w*v1.w;
        *reinterpret_cast<short8*>(bpre + (size_t)(nb * 2048 + kk * 512 + lane * 8))
            = cvt8(v0, v1);
    }
    sq += __shfl_xor(sq, 16);
    sq += __shfl_xor(sq, 32);
    if (lane < 16)
        c2p[nb * 16 + lane] = ((nb * 16 + lane) < C_N) ? sq : 1e30f;
}

// ---- kernel 2: block = 128 rows x 128 cols. B slice in LDS, 4 waves x 32
// rows, inner loop pure {ds_read_b128, MFMA, hinge}.
__global__ __launch_bounds__(256, 4) void closs_kernel(
    const float* __restrict__ feat, const int* __restrict__ tgt,
    const short* __restrict__ bpre, const float* __restrict__ c2p,
    float* __restrict__ part)
{
    __shared__ short Bs[8 * 2048];   // 8 col-blocks x 2048 shorts = 32 KiB

    const int tid  = threadIdx.x;
    const int wave = tid >> 6;
    const int lane = tid & 63;
    const int l15  = lane & 15;
    const int kg   = lane >> 4;
    const int bx   = blockIdx.x;                 // col split 0..7
    const int row0 = blockIdx.y * 128 + wave * 32;

    // ---- stage B slice (linear 32 KiB copy, fragment-order already) ----
    {
        const short8* gsrc = reinterpret_cast<const short8*>(bpre) + (size_t)bx * 2048;
        short8* ldst = reinterpret_cast<short8*>(Bs);
        #pragma unroll
        for (int i = 0; i < 8; ++i)
            ldst[tid + i * 256] = gsrc[tid + i * 256];
    }

    // ---- A prologue: 32 rows x K=128 to registers + f2 (overlaps staging) ----
    short8 a[2][4];
    float  t[2][4];
    int    tg[2][4];
    #pragma unroll
    for (int rg = 0; rg < 2; ++rg) {
        const float* ap = feat + (size_t)(row0 + rg * 16 + l15) * D_N + kg * 8;
        float s = 0.f;
        #pragma unroll
        for (int kk = 0; kk < 4; ++kk) {
            float4 v0 = *reinterpret_cast<const float4*>(ap + kk * 32);
            float4 v1 = *reinterpret_cast<const float4*>(ap + kk * 32 + 4);
            s += v0.x*v0.x + v0.y*v0.y + v0.z*v0.z + v0.w*v0.w
               + v1.x*v1.x + v1.y*v1.y + v1.z*v1.z + v1.w*v1.w;
            a[rg][kk] = cvt8(v0, v1);
        }
        s += __shfl_xor(s, 16);
        s += __shfl_xor(s, 32);
        #pragma unroll
        for (int r = 0; r < 4; ++r) {
            t[rg][r]  = MARGIN - __shfl(s, kg * 4 + r);
            tg[rg][r] = tgt[row0 + rg * 16 + kg * 4 + r];
        }
    }
    __syncthreads();

    // ---- main loop: 8 col-blocks ----
    float hsum = 0.f;
    #pragma unroll
    for (int nb = 0; nb < 8; ++nb) {
        const short8* bp = reinterpret_cast<const short8*>(Bs + nb * 2048) + lane;
        short8 b0 = bp[0];
        short8 b1 = bp[64];
        short8 b2 = bp[128];
        short8 b3 = bp[192];
        f32x4 acc0 = (f32x4){0.f, 0.f, 0.f, 0.f};
        f32x4 acc1 = (f32x4){0.f, 0.f, 0.f, 0.f};
        acc0 = __builtin_amdgcn_mfma_f32_16x16x32_bf16(a[0][0], b0, acc0, 0, 0, 0);
        acc1 = __builtin_amdgcn_mfma_f32_16x16x32_bf16(a[1][0], b0, acc1, 0, 0, 0);
        acc0 = __builtin_amdgcn_mfma_f32_16x16x32_bf16(a[0][1], b1, acc0, 0, 0, 0);
        acc1 = __builtin_amdgcn_mfma_f32_16x16x32_bf16(a[1][1], b1, acc1, 0, 0, 0);
        acc0 = __builtin_amdgcn_mfma_f32_16x16x32_bf16(a[0][2], b2, acc0, 0, 0, 0);
        acc1 = __builtin_amdgcn_mfma_f32_16x16x32_bf16(a[1][2], b2, acc1, 0, 0, 0);
        acc0 = __builtin_amdgcn_mfma_f32_16x16x32_bf16(a[0][3], b3, acc0, 0, 0, 0);
        acc1 = __builtin_amdgcn_mfma_f32_16x16x32_bf16(a[1][3], b3, acc1, 0, 0, 0);

        // C/D layout (m89): col = lane&15, row = kg*4 + r.
        const int   col = (bx * 8 + nb) * 16 + l15;
        const float c2v = c2p[col];     // 1e30 sentinel for padded cols -> h=0
        #pragma unroll
        for (int r = 0; r < 4; ++r) {
            const float u0 = __builtin_fmaf(2.0f, acc0[r], t[0][r] - c2v);
            hsum += (col != tg[0][r]) ? fmaxf(0.0f, u0) : 0.0f;
            const float u1 = __builtin_fmaf(2.0f, acc1[r], t[1][r] - c2v);
            hsum += (col != tg[1][r]) ? fmaxf(0.0f, u1) : 0.0f;
        }
    }

    // ---- reduce: wave -> block -> plain store (no contended atomics) ----
    #pragma unroll
    for (int off = 32; off; off >>= 1) hsum += __shfl_down(hsum, off);
    __shared__ float ws[4];
    if (lane == 0) ws[wave] = hsum;
    __syncthreads();
    if (tid == 0)
        part[blockIdx.y * gridDim.x + blockIdx.x] = ws[0] + ws[1] + ws[2] + ws[3];
}

// ---- kernel 3: reduce 1024 partials -> out[0] ----
__global__ __launch_bounds__(256) void reduce_kernel(
    const float* __restrict__ part, float* __restrict__ out)
{
    const int tid = threadIdx.x;
    float s = part[tid] + part[tid + 256] + part[tid + 512] + part[tid + 768];
    #pragma unroll
    for (int off = 32; off; off >>= 1) s += __shfl_down(s, off);
    __shared__ float ws[4];
    if ((tid & 63) == 0) ws[tid >> 6] = s;
    __syncthreads();
    if (tid == 0) out[0] = (ws[0] + ws[1] + ws[2] + ws[3]) * (1.0f / 16384.0f);
}

extern "C" void kernel_launch(void* const* d_in, const int* in_sizes, int n_in,
                              void* d_out, int out_size, void* d_ws, size_t ws_size,
                              hipStream_t stream) {
    const float* feat = (const float*)d_in[0];
    const int*   tgt  = (const int*)d_in[1];
    const float* cls  = (const float*)d_in[2];
    float*       out  = (float*)d_out;

    short* bpre = (short*)d_ws;                                      // 256 KiB
    float* c2p  = (float*)((char*)d_ws + 64 * 2048 * sizeof(short)); // 4 KiB
    float* part = c2p + 1024;                                        // 4 KiB

    prep_kernel<<<64, 64, 0, stream>>>(cls, bpre, c2p);
    closs_kernel<<<dim3(8, 128), 256, 0, stream>>>(feat, tgt, bpre, c2p, part);
    reduce_kernel<<<1, 256, 0, stream>>>(part, out);
}